// Round 1
// baseline (700.432 us; speedup 1.0000x reference)
//
#include <hip/hip_runtime.h>
#include <hip/hip_bf16.h>
#include <math.h>

#define BB 4
#define NN 2046
#define IND 512
#define DD 1024
#define HH 16
#define DHH 64
#define SS 2048
#define MM (BB*NN)          // 8184 token rows
#define EPSV 1e-5f

// workspace layout (float offsets)
#define WS_SCORES 0                       // [B][2][16][S] = 262144 floats
#define WS_U      (BB*2*HH*SS)            // [2][1024]
#define WS_G      (WS_U + 2*DD)           // [2][16]
#define WS_C2     (WS_G + 32)             // [2][16]

__device__ __forceinline__ float blockReduceSum(float v, volatile float* buf4) {
  #pragma unroll
  for (int m = 32; m >= 1; m >>= 1) v += __shfl_xor(v, m, 64);
  int wid = threadIdx.x >> 6;
  __syncthreads();
  if ((threadIdx.x & 63) == 0) buf4[wid] = v;
  __syncthreads();
  return buf4[0] + buf4[1] + buf4[2] + buf4[3];
}

__device__ __forceinline__ float blockReduceMax(float v, volatile float* buf4) {
  #pragma unroll
  for (int m = 32; m >= 1; m >>= 1) v = fmaxf(v, __shfl_xor(v, m, 64));
  int wid = threadIdx.x >> 6;
  __syncthreads();
  if ((threadIdx.x & 63) == 0) buf4[wid] = v;
  __syncthreads();
  return fmaxf(fmaxf(buf4[0], buf4[1]), fmaxf(buf4[2], buf4[3]));
}

// ---------------------------------------------------------------------------
// Stage A: LN the two special token rows, compute q (2 rows), fold Wk into
// wtil = Wk[h] @ q / sqrt(64), emit per-(h,s) constants G, C2, the u-vectors
// (g[d]*wtil), and the t=0,1 score entries for every batch.
// ---------------------------------------------------------------------------
__global__ __launch_bounds__(256) void stageA(
    const float* __restrict__ tt, const float* __restrict__ ct,
    const float* __restrict__ lng, const float* __restrict__ lnb,
    const float* __restrict__ Wq, const float* __restrict__ bq,
    const float* __restrict__ Wk, const float* __restrict__ bk,
    float* __restrict__ ws) {
  __shared__ float hrow[2][DD];
  __shared__ float qsm[2][HH][DHH];
  __shared__ float wt[2][HH][DHH];
  __shared__ float csm[2][HH];
  __shared__ float rbuf[4];
  const int t = threadIdx.x;

  // LayerNorm of the two broadcast token rows (batch-independent)
  for (int s = 0; s < 2; ++s) {
    const float* src = (s == 0) ? tt : ct;
    float v[4];
    float s1 = 0.f, s2 = 0.f;
    #pragma unroll
    for (int i = 0; i < 4; ++i) { v[i] = src[t*4+i]; s1 += v[i]; s2 += v[i]*v[i]; }
    s1 = blockReduceSum(s1, rbuf);
    s2 = blockReduceSum(s2, rbuf);
    float mu  = s1 * (1.f/DD);
    float var = s2 * (1.f/DD) - mu*mu;
    float rstd = rsqrtf(var + EPSV);
    #pragma unroll
    for (int i = 0; i < 4; ++i) {
      int d = t*4+i;
      hrow[s][d] = (v[i]-mu)*rstd*lng[d] + lnb[d];
    }
  }
  __syncthreads();

  // q[s][h][e] = sum_d hrow[s][h*64+d] * Wq[h][d][e] + bq[h][e]
  {
    const int e  = t & 63;
    const int hw = t >> 6;
    for (int s = 0; s < 2; ++s)
      for (int hb = 0; hb < 4; ++hb) {
        int h = hb*4 + hw;
        float acc = bq[h*64+e];
        #pragma unroll 8
        for (int d = 0; d < 64; ++d)
          acc += hrow[s][h*64+d] * Wq[(h*64+d)*64+e];
        qsm[s][h][e] = acc;
      }
  }
  __syncthreads();

  // wtil[s][h][d] = (sum_e Wk[h][d][e] * q[s][h][e]) / 8
  {
    const int d  = t & 63;
    const int hw = t >> 6;
    for (int s = 0; s < 2; ++s)
      for (int hb = 0; hb < 4; ++hb) {
        int h = hb*4 + hw;
        float acc = 0.f;
        #pragma unroll 8
        for (int e = 0; e < 64; ++e)
          acc += Wk[(h*64+d)*64+e] * qsm[s][h][e];
        wt[s][h][d] = acc * 0.125f;
      }
  }
  __syncthreads();

  if (t < 32) {            // c[s][h] = q . bk / 8
    int s = t >> 4, h = t & 15;
    float acc = 0.f;
    for (int e = 0; e < 64; ++e) acc += qsm[s][h][e] * bk[h*64+e];
    csm[s][h] = acc * 0.125f;
  }
  __syncthreads();

  // u_s[d] = g[d] * wtil[s][d/64][d%64]
  for (int s = 0; s < 2; ++s) {
    #pragma unroll
    for (int i = 0; i < 4; ++i) {
      int d = t*4+i;
      ws[WS_U + s*DD + d] = lng[d] * wt[s][d>>6][d&63];
    }
  }
  if (t < 32) {
    int s = t >> 4, h = t & 15;
    float G = 0.f, C = 0.f, st0 = 0.f, st1 = 0.f;
    for (int dd = 0; dd < 64; ++dd) {
      int d = h*64+dd;
      float w = wt[s][h][dd];
      G   += lng[d]*w;
      C   += lnb[d]*w;
      st0 += hrow[0][d]*w;
      st1 += hrow[1][d]*w;
    }
    ws[WS_G  + s*16 + h] = G;
    ws[WS_C2 + s*16 + h] = C + csm[s][h];
    float sc0 = st0 + csm[s][h];
    float sc1 = st1 + csm[s][h];
    for (int b = 0; b < BB; ++b) {
      float* sp = ws + WS_SCORES + (size_t)((b*2+s)*16 + h) * SS;
      sp[0] = sc0;  // key position t=0 (time token)
      sp[1] = sc1;  // key position t=1 (cluster token)
    }
  }
}

// ---------------------------------------------------------------------------
// Stage B: for 32 x-rows per block, compute token = x@W_map + b_map in fp32
// register tiles, and fold each 64-col chunk (== one head) directly into the
// LN+score reductions. Only 32 score floats leave the block per row.
// ---------------------------------------------------------------------------
__global__ __launch_bounds__(256, 2) void stageB(
    const float* __restrict__ x, const float* __restrict__ Wm,
    const float* __restrict__ bmap, float* __restrict__ ws) {
  __shared__ float xs[32*516];          // 32 rows x 512 K, stride 516 (bank-safe)
  __shared__ float Asm[32][16][2];
  __shared__ float ssum[32][2];
  const int t  = threadIdx.x;
  const int m0 = blockIdx.x * 32;

  // stage x tile (zero-fill past M)
  #pragma unroll
  for (int i = 0; i < 16; ++i) {
    int idx = i*256 + t;
    int row = idx >> 7, f4 = idx & 127;
    int m = m0 + row;
    float4 v = make_float4(0.f,0.f,0.f,0.f);
    if (m < MM) v = *(const float4*)(x + (size_t)m*IND + f4*4);
    *(float4*)(&xs[row*516 + f4*4]) = v;
  }
  __syncthreads();

  const int cg = t & 15, rg = t >> 4;
  const int r0 = rg*2, r1 = r0+1;
  float s1a = 0.f, s2a = 0.f, s1b = 0.f, s2b = 0.f;

  for (int chunk = 0; chunk < 16; ++chunk) {       // chunk == head
    const int c0 = chunk*64 + cg*4;
    float a00=0,a01=0,a02=0,a03=0, a10=0,a11=0,a12=0,a13=0;
    const float* wp = Wm + c0;
    const float4* xa4 = (const float4*)(&xs[r0*516]);
    const float4* xb4 = (const float4*)(&xs[r1*516]);
    for (int k4 = 0; k4 < 128; ++k4) {
      float4 xa = xa4[k4];
      float4 xb = xb4[k4];
      #pragma unroll
      for (int kk = 0; kk < 4; ++kk) {
        float4 w = *(const float4*)(wp + (size_t)(k4*4+kk)*DD);
        float fa = (kk==0)?xa.x:(kk==1)?xa.y:(kk==2)?xa.z:xa.w;
        float fb = (kk==0)?xb.x:(kk==1)?xb.y:(kk==2)?xb.z:xb.w;
        a00 += fa*w.x; a01 += fa*w.y; a02 += fa*w.z; a03 += fa*w.w;
        a10 += fb*w.x; a11 += fb*w.y; a12 += fb*w.z; a13 += fb*w.w;
      }
    }
    float4 bm = *(const float4*)(bmap + c0);
    a00+=bm.x; a01+=bm.y; a02+=bm.z; a03+=bm.w;
    a10+=bm.x; a11+=bm.y; a12+=bm.z; a13+=bm.w;

    float4 u0 = *(const float4*)(ws + WS_U + c0);
    float4 u1 = *(const float4*)(ws + WS_U + DD + c0);

    {
      float p0 = a00*u0.x + a01*u0.y + a02*u0.z + a03*u0.w;
      float p1 = a00*u1.x + a01*u1.y + a02*u1.z + a03*u1.w;
      s1a += a00+a01+a02+a03;
      s2a += a00*a00+a01*a01+a02*a02+a03*a03;
      #pragma unroll
      for (int msk = 8; msk >= 1; msk >>= 1) {
        p0 += __shfl_xor(p0, msk, 64);
        p1 += __shfl_xor(p1, msk, 64);
      }
      if (cg == 0) { Asm[r0][chunk][0] = p0; Asm[r0][chunk][1] = p1; }
    }
    {
      float p0 = a10*u0.x + a11*u0.y + a12*u0.z + a13*u0.w;
      float p1 = a10*u1.x + a11*u1.y + a12*u1.z + a13*u1.w;
      s1b += a10+a11+a12+a13;
      s2b += a10*a10+a11*a11+a12*a12+a13*a13;
      #pragma unroll
      for (int msk = 8; msk >= 1; msk >>= 1) {
        p0 += __shfl_xor(p0, msk, 64);
        p1 += __shfl_xor(p1, msk, 64);
      }
      if (cg == 0) { Asm[r1][chunk][0] = p0; Asm[r1][chunk][1] = p1; }
    }
  }

  #pragma unroll
  for (int msk = 8; msk >= 1; msk >>= 1) {
    s1a += __shfl_xor(s1a, msk, 64);
    s2a += __shfl_xor(s2a, msk, 64);
    s1b += __shfl_xor(s1b, msk, 64);
    s2b += __shfl_xor(s2b, msk, 64);
  }
  if (cg == 0) {
    ssum[r0][0] = s1a; ssum[r0][1] = s2a;
    ssum[r1][0] = s1b; ssum[r1][1] = s2b;
  }
  __syncthreads();

  // finalize: score = rstd*(A - mu*G) + C2, scatter into [b][s][h][t]
  #pragma unroll
  for (int i = 0; i < 4; ++i) {
    int idx = t*4 + i;
    int row = idx >> 5, hs = idx & 31;
    int h = hs & 15, s = hs >> 4;
    int m = m0 + row;
    if (m >= MM) continue;
    float mu   = ssum[row][0] * (1.f/DD);
    float var  = ssum[row][1] * (1.f/DD) - mu*mu;
    float rstd = rsqrtf(var + EPSV);
    float score = rstd * (Asm[row][h][s] - mu * ws[WS_G + s*16+h]) + ws[WS_C2 + s*16+h];
    int b  = m / NN;
    int tp = m - b*NN + 2;
    ws[WS_SCORES + (size_t)((b*2+s)*16 + h)*SS + tp] = score;
  }
}

// ---------------------------------------------------------------------------
// Stage C: per (b,s): softmax over t for each of 16 heads, mean over heads.
// ---------------------------------------------------------------------------
__global__ __launch_bounds__(256) void stageC(const float* __restrict__ ws,
                                              float* __restrict__ out) {
  __shared__ float rbuf[4];
  const int bs = blockIdx.x;   // b*2+s
  const int t  = threadIdx.x;
  float acc[8];
  #pragma unroll
  for (int i = 0; i < 8; ++i) acc[i] = 0.f;

  for (int h = 0; h < 16; ++h) {
    const float* row = ws + WS_SCORES + (size_t)(bs*16 + h)*SS;
    float v[8];
    float mx = -3.0e38f;
    #pragma unroll
    for (int i = 0; i < 8; ++i) { v[i] = row[i*256 + t]; mx = fmaxf(mx, v[i]); }
    mx = blockReduceMax(mx, rbuf);
    float sum = 0.f;
    #pragma unroll
    for (int i = 0; i < 8; ++i) { v[i] = __expf(v[i]-mx); sum += v[i]; }
    sum = blockReduceSum(sum, rbuf);
    float inv = 1.f / (16.f * sum);
    #pragma unroll
    for (int i = 0; i < 8; ++i) acc[i] += v[i]*inv;
  }
  const int b = bs >> 1, s = bs & 1;
  #pragma unroll
  for (int i = 0; i < 8; ++i)
    out[(size_t)s*(BB*SS) + b*SS + i*256 + t] = acc[i];
}

extern "C" void kernel_launch(void* const* d_in, const int* in_sizes, int n_in,
                              void* d_out, int out_size, void* d_ws, size_t ws_size,
                              hipStream_t stream) {
  const float* x   = (const float*)d_in[0];
  const float* Wm  = (const float*)d_in[1];
  const float* bm  = (const float*)d_in[2];
  const float* tt  = (const float*)d_in[3];
  const float* ct  = (const float*)d_in[4];
  const float* lng = (const float*)d_in[5];
  const float* lnb = (const float*)d_in[6];
  const float* Wq  = (const float*)d_in[7];
  const float* bq  = (const float*)d_in[8];
  const float* Wk  = (const float*)d_in[9];
  const float* bk  = (const float*)d_in[10];
  float* ws  = (float*)d_ws;
  float* out = (float*)d_out;

  hipLaunchKernelGGL(stageA, dim3(1),   dim3(256), 0, stream,
                     tt, ct, lng, lnb, Wq, bq, Wk, bk, ws);
  hipLaunchKernelGGL(stageB, dim3(256), dim3(256), 0, stream, x, Wm, bm, ws);
  hipLaunchKernelGGL(stageC, dim3(8),   dim3(256), 0, stream, ws, out);
}

// Round 2
// 280.865 us; speedup vs baseline: 2.4938x; 2.4938x over previous
//
#include <hip/hip_runtime.h>
#include <hip/hip_bf16.h>
#include <math.h>

#define BB 4
#define NN 2046
#define IND 512
#define DD 1024
#define HH 16
#define SS 2048
#define MM (BB*NN)          // 8184 real token rows; padded to 8192
#define MPAD 8192
#define ROWPAD 8256         // A-buffer row stride (specials at 8192/8193)
#define EPSV 1e-5f

// ---- workspace byte offsets ----
#define OFF_U    0              // float[2][1024]
#define OFF_G    8192           // float[32]
#define OFF_C2   8320           // float[32]
#define OFF_S12  16384          // float[(8192+2+pad)][4] : [row][nside][{s1,s2}]
#define OFF_A    151552         // float[2][16][ROWPAD]
#define OFF_XH   1212416        // bf16[8192][512]
#define OFF_XL   9601024        // bf16[8192][512]
#define OFF_WHT  17989632       // bf16[1024][512]  (transposed W, hi)
#define OFF_WLT  19038208       // bf16[1024][512]  (transposed W, lo)

typedef float f32x4 __attribute__((ext_vector_type(4)));
typedef __bf16 bf16x8 __attribute__((ext_vector_type(8)));
typedef unsigned short u16x8 __attribute__((ext_vector_type(8)));

__device__ __forceinline__ unsigned short f2bf_rne(float f) {
  unsigned int u = __float_as_uint(f);
  u += 0x7FFFu + ((u >> 16) & 1u);
  return (unsigned short)(u >> 16);
}
__device__ __forceinline__ float bf2f(unsigned short h) {
  return __uint_as_float(((unsigned int)h) << 16);
}

__device__ __forceinline__ float blockReduceSum(float v, volatile float* buf4) {
  #pragma unroll
  for (int m = 32; m >= 1; m >>= 1) v += __shfl_xor(v, m, 64);
  int wid = threadIdx.x >> 6;
  __syncthreads();
  if ((threadIdx.x & 63) == 0) buf4[wid] = v;
  __syncthreads();
  return buf4[0] + buf4[1] + buf4[2] + buf4[3];
}

__device__ __forceinline__ float blockReduceMax(float v, volatile float* buf4) {
  #pragma unroll
  for (int m = 32; m >= 1; m >>= 1) v = fmaxf(v, __shfl_xor(v, m, 64));
  int wid = threadIdx.x >> 6;
  __syncthreads();
  if ((threadIdx.x & 63) == 0) buf4[wid] = v;
  __syncthreads();
  return fmaxf(fmaxf(buf4[0], buf4[1]), fmaxf(buf4[2], buf4[3]));
}

// ---------------------------------------------------------------------------
// convX: x (fp32 [8184][512]) -> xh/xl bf16 split, rows padded to 8192 w/ 0.
// ---------------------------------------------------------------------------
__global__ __launch_bounds__(256) void convX(const float* __restrict__ x,
                                             unsigned short* __restrict__ xh,
                                             unsigned short* __restrict__ xl) {
  const int t = threadIdx.x;
  const int row = blockIdx.x * 4 + (t >> 6);
  const int c0 = (t & 63) * 8;
  const size_t po = (size_t)row * IND + c0;
  u16x8 hv, lv;
  if (row < MM) {
    #pragma unroll
    for (int i = 0; i < 8; ++i) {
      float v = x[po + i];
      unsigned short hh = f2bf_rne(v);
      hv[i] = hh;
      lv[i] = f2bf_rne(v - bf2f(hh));
    }
  } else {
    #pragma unroll
    for (int i = 0; i < 8; ++i) { hv[i] = 0; lv[i] = 0; }
  }
  *(u16x8*)(xh + po) = hv;
  *(u16x8*)(xl + po) = lv;
}

// ---------------------------------------------------------------------------
// convW: W_map fp32 [512][1024] -> transposed bf16 split [1024][512].
// ---------------------------------------------------------------------------
__global__ __launch_bounds__(256) void convW(const float* __restrict__ Wm,
                                             unsigned short* __restrict__ wht,
                                             unsigned short* __restrict__ wlt) {
  const int t = threadIdx.x;
  const int n = blockIdx.x * 4 + (t >> 6);
  const int k0 = (t & 63) * 8;
  u16x8 hv, lv;
  #pragma unroll
  for (int i = 0; i < 8; ++i) {
    float v = Wm[(size_t)(k0 + i) * DD + n];
    unsigned short hh = f2bf_rne(v);
    hv[i] = hh;
    lv[i] = f2bf_rne(v - bf2f(hh));
  }
  *(u16x8*)(wht + (size_t)n * IND + k0) = hv;
  *(u16x8*)(wlt + (size_t)n * IND + k0) = lv;
}

// ---------------------------------------------------------------------------
// stageA: LN the two special rows, q = hh@Wq+bq, wtil = Wk@q/8, emit
// u = g*wtil, G, C2, plus S12/A entries for the special rows (8192/8193).
// ---------------------------------------------------------------------------
__global__ __launch_bounds__(256) void stageA(
    const float* __restrict__ tt, const float* __restrict__ ct,
    const float* __restrict__ lng, const float* __restrict__ lnb,
    const float* __restrict__ Wq, const float* __restrict__ bq,
    const float* __restrict__ Wk, const float* __restrict__ bk,
    float* __restrict__ ws) {
  __shared__ float raw[2][DD];
  __shared__ float hrow[2][DD];
  __shared__ float qsm[2][HH][64];
  __shared__ float wt[2][HH][64];
  __shared__ float csm[2][HH];
  __shared__ float rbuf[4];
  const int t = threadIdx.x;
  float* U   = ws + OFF_U/4;
  float* Gp  = ws + OFF_G/4;
  float* C2p = ws + OFF_C2/4;
  float* s12 = ws + OFF_S12/4;
  float* Ap  = ws + OFF_A/4;

  for (int s = 0; s < 2; ++s) {
    const float* src = (s == 0) ? tt : ct;
    float v[4];
    float s1 = 0.f, s2 = 0.f;
    #pragma unroll
    for (int i = 0; i < 4; ++i) {
      v[i] = src[t*4+i]; raw[s][t*4+i] = v[i];
      s1 += v[i]; s2 += v[i]*v[i];
    }
    s1 = blockReduceSum(s1, rbuf);
    s2 = blockReduceSum(s2, rbuf);
    if (t == 0) {
      s12[(size_t)(MPAD+s)*4 + 0] = s1;
      s12[(size_t)(MPAD+s)*4 + 1] = s2;
      s12[(size_t)(MPAD+s)*4 + 2] = 0.f;
      s12[(size_t)(MPAD+s)*4 + 3] = 0.f;
    }
    float mu  = s1 * (1.f/DD);
    float var = s2 * (1.f/DD) - mu*mu;
    float rstd = rsqrtf(var + EPSV);
    #pragma unroll
    for (int i = 0; i < 4; ++i) {
      int d = t*4+i;
      hrow[s][d] = (v[i]-mu)*rstd*lng[d] + lnb[d];
    }
  }
  __syncthreads();

  {  // q
    const int e = t & 63, hw = t >> 6;
    for (int s = 0; s < 2; ++s)
      for (int hb = 0; hb < 4; ++hb) {
        int h = hb*4 + hw;
        float acc = bq[h*64+e];
        #pragma unroll 8
        for (int d = 0; d < 64; ++d)
          acc += hrow[s][h*64+d] * Wq[(h*64+d)*64+e];
        qsm[s][h][e] = acc;
      }
  }
  __syncthreads();

  {  // wtil
    const int d = t & 63, hw = t >> 6;
    for (int s = 0; s < 2; ++s)
      for (int hb = 0; hb < 4; ++hb) {
        int h = hb*4 + hw;
        float acc = 0.f;
        #pragma unroll 8
        for (int e = 0; e < 64; ++e)
          acc += Wk[(h*64+d)*64+e] * qsm[s][h][e];
        wt[s][h][d] = acc * 0.125f;
      }
  }
  __syncthreads();

  if (t < 32) {
    int s = t >> 4, h = t & 15;
    float acc = 0.f;
    for (int e = 0; e < 64; ++e) acc += qsm[s][h][e] * bk[h*64+e];
    csm[s][h] = acc * 0.125f;
  }
  __syncthreads();

  for (int s = 0; s < 2; ++s) {
    #pragma unroll
    for (int i = 0; i < 4; ++i) {
      int d = t*4+i;
      U[s*DD + d] = lng[d] * wt[s][d>>6][d&63];
    }
  }
  if (t < 32) {
    int s = t >> 4, h = t & 15;
    float G = 0.f, C = 0.f, a0 = 0.f, a1 = 0.f;
    for (int dd = 0; dd < 64; ++dd) {
      int d = h*64+dd;
      float w = wt[s][h][dd];
      float uu = lng[d]*w;
      G  += lng[d]*w;
      C  += lnb[d]*w;
      a0 += raw[0][d]*uu;
      a1 += raw[1][d]*uu;
    }
    Gp[s*16+h]  = G;
    C2p[s*16+h] = C + csm[s][h];
    Ap[(size_t)(s*16+h)*ROWPAD + MPAD + 0] = a0;
    Ap[(size_t)(s*16+h)*ROWPAD + MPAD + 1] = a1;
  }
}

// ---------------------------------------------------------------------------
// stageB: MFMA GEMM tile 16 rows x 512 cols, K=512, split-bf16 (3 products).
// Epilogue reduces S1, S2, per-head A directly from C-fragments.
// grid = 512 m-tiles x 2 n-sides = 1024 blocks, 256 threads (4 waves).
// ---------------------------------------------------------------------------
__global__ __launch_bounds__(256, 4) void stageB(
    const unsigned short* __restrict__ xh, const unsigned short* __restrict__ xl,
    const unsigned short* __restrict__ wht, const unsigned short* __restrict__ wlt,
    const float* __restrict__ bmap, float* __restrict__ ws) {
  __shared__ float s12sm[4][16][2];
  const int t = threadIdx.x;
  const int wave = t >> 6, lane = t & 63;
  const int lj = lane & 15, lg = lane >> 4;
  const int mt = blockIdx.x >> 1, nside = blockIdx.x & 1;
  const int m0 = mt * 16;
  const int colbase = nside*512 + wave*128;
  const float* U   = ws + OFF_U/4;
  float* s12 = ws + OFF_S12/4;
  float* Ap  = ws + OFF_A/4;

  f32x4 acc[8];
  #pragma unroll
  for (int c = 0; c < 8; ++c) acc[c] = (f32x4){0.f,0.f,0.f,0.f};

  const unsigned short* ap_h = xh + (size_t)(m0 + lj)*IND + lg*8;
  const unsigned short* ap_l = xl + (size_t)(m0 + lj)*IND + lg*8;
  const unsigned short* bp_h = wht + (size_t)(colbase + lj)*IND + lg*8;
  const unsigned short* bp_l = wlt + (size_t)(colbase + lj)*IND + lg*8;

  for (int kk = 0; kk < 16; ++kk) {
    const int ko = kk * 32;
    bf16x8 ah = *(const bf16x8*)(ap_h + ko);
    bf16x8 al = *(const bf16x8*)(ap_l + ko);
    #pragma unroll
    for (int c = 0; c < 8; ++c) {
      bf16x8 bh = *(const bf16x8*)(bp_h + (size_t)c*16*IND + ko);
      bf16x8 bl = *(const bf16x8*)(bp_l + (size_t)c*16*IND + ko);
      acc[c] = __builtin_amdgcn_mfma_f32_16x16x32_bf16(ah, bh, acc[c], 0, 0, 0);
      acc[c] = __builtin_amdgcn_mfma_f32_16x16x32_bf16(al, bh, acc[c], 0, 0, 0);
      acc[c] = __builtin_amdgcn_mfma_f32_16x16x32_bf16(ah, bl, acc[c], 0, 0, 0);
    }
  }

  // epilogue: D[i][j] in acc[c][r]: token row = m0 + lg*4 + r, col = colbase + c*16 + lj
  float s1[4] = {0.f,0.f,0.f,0.f};
  float s2[4] = {0.f,0.f,0.f,0.f};
  float aAcc[2][2][4];
  #pragma unroll
  for (int ch = 0; ch < 2; ++ch)
    #pragma unroll
    for (int sq = 0; sq < 2; ++sq)
      #pragma unroll
      for (int r = 0; r < 4; ++r) aAcc[ch][sq][r] = 0.f;

  #pragma unroll
  for (int c = 0; c < 8; ++c) {
    const int gc = colbase + c*16 + lj;
    const float bmv = bmap[gc];
    const float u0 = U[gc];
    const float u1 = U[DD + gc];
    const int ch = c >> 2;
    #pragma unroll
    for (int r = 0; r < 4; ++r) {
      float tok = acc[c][r] + bmv;
      s1[r] += tok;
      s2[r] += tok*tok;
      aAcc[ch][0][r] += tok*u0;
      aAcc[ch][1][r] += tok*u1;
    }
  }

  // reduce over the 16 column-lanes (lj)
  #pragma unroll
  for (int msk = 8; msk >= 1; msk >>= 1) {
    #pragma unroll
    for (int r = 0; r < 4; ++r) {
      s1[r] += __shfl_xor(s1[r], msk, 64);
      s2[r] += __shfl_xor(s2[r], msk, 64);
      #pragma unroll
      for (int ch = 0; ch < 2; ++ch)
        #pragma unroll
        for (int sq = 0; sq < 2; ++sq)
          aAcc[ch][sq][r] += __shfl_xor(aAcc[ch][sq][r], msk, 64);
    }
  }

  if (lj == 0) {
    #pragma unroll
    for (int r = 0; r < 4; ++r) {
      s12sm[wave][lg*4+r][0] = s1[r];
      s12sm[wave][lg*4+r][1] = s2[r];
    }
    #pragma unroll
    for (int ch = 0; ch < 2; ++ch) {
      const int h = nside*8 + wave*2 + ch;
      #pragma unroll
      for (int sq = 0; sq < 2; ++sq)
        #pragma unroll
        for (int r = 0; r < 4; ++r)
          Ap[(size_t)(sq*16+h)*ROWPAD + m0 + lg*4 + r] = aAcc[ch][sq][r];
    }
  }
  __syncthreads();
  if (t < 32) {
    const int rl = t >> 1, q = t & 1;
    float v = s12sm[0][rl][q] + s12sm[1][rl][q] + s12sm[2][rl][q] + s12sm[3][rl][q];
    s12[(size_t)(m0 + rl)*4 + nside*2 + q] = v;
  }
}

// ---------------------------------------------------------------------------
// stageC: per (b,s): reconstruct scores from A/S12, softmax over t per head,
// mean over heads.
// ---------------------------------------------------------------------------
__global__ __launch_bounds__(256) void stageC(const float* __restrict__ ws,
                                              float* __restrict__ out) {
  __shared__ float rbuf[4];
  const int bs = blockIdx.x, b = bs >> 1, s = bs & 1;
  const int t = threadIdx.x;
  const float* s12 = ws + OFF_S12/4;
  const float* Ap  = ws + OFF_A/4;
  const float* Gp  = ws + OFF_G/4;
  const float* C2p = ws + OFF_C2/4;

  int ridx[8]; float mu[8], rstd[8];
  #pragma unroll
  for (int i = 0; i < 8; ++i) {
    int p = i*256 + t;
    int r = (p == 0) ? MPAD : (p == 1) ? (MPAD+1) : (b*NN + p - 2);
    ridx[i] = r;
    float s1 = s12[(size_t)r*4+0] + s12[(size_t)r*4+2];
    float s2 = s12[(size_t)r*4+1] + s12[(size_t)r*4+3];
    float m  = s1 * (1.f/DD);
    float va = s2 * (1.f/DD) - m*m;
    mu[i] = m;
    rstd[i] = rsqrtf(va + EPSV);
  }

  float accv[8];
  #pragma unroll
  for (int i = 0; i < 8; ++i) accv[i] = 0.f;

  for (int h = 0; h < 16; ++h) {
    const float Gh = Gp[s*16+h], Ch = C2p[s*16+h];
    const float* Ah = Ap + (size_t)(s*16+h)*ROWPAD;
    float v[8];
    float mx = -3.0e38f;
    #pragma unroll
    for (int i = 0; i < 8; ++i) {
      v[i] = rstd[i]*(Ah[ridx[i]] - mu[i]*Gh) + Ch;
      mx = fmaxf(mx, v[i]);
    }
    mx = blockReduceMax(mx, rbuf);
    float sum = 0.f;
    #pragma unroll
    for (int i = 0; i < 8; ++i) { v[i] = __expf(v[i]-mx); sum += v[i]; }
    sum = blockReduceSum(sum, rbuf);
    float inv = 1.f / (16.f * sum);
    #pragma unroll
    for (int i = 0; i < 8; ++i) accv[i] += v[i]*inv;
  }
  #pragma unroll
  for (int i = 0; i < 8; ++i)
    out[(size_t)s*(BB*SS) + (size_t)b*SS + i*256 + t] = accv[i];
}

extern "C" void kernel_launch(void* const* d_in, const int* in_sizes, int n_in,
                              void* d_out, int out_size, void* d_ws, size_t ws_size,
                              hipStream_t stream) {
  const float* x   = (const float*)d_in[0];
  const float* Wm  = (const float*)d_in[1];
  const float* bm  = (const float*)d_in[2];
  const float* tt  = (const float*)d_in[3];
  const float* ct  = (const float*)d_in[4];
  const float* lng = (const float*)d_in[5];
  const float* lnb = (const float*)d_in[6];
  const float* Wq  = (const float*)d_in[7];
  const float* bq  = (const float*)d_in[8];
  const float* Wk  = (const float*)d_in[9];
  const float* bk  = (const float*)d_in[10];
  char* wsb = (char*)d_ws;
  float* ws = (float*)d_ws;
  float* out = (float*)d_out;

  unsigned short* xh  = (unsigned short*)(wsb + OFF_XH);
  unsigned short* xlp = (unsigned short*)(wsb + OFF_XL);
  unsigned short* wht = (unsigned short*)(wsb + OFF_WHT);
  unsigned short* wlt = (unsigned short*)(wsb + OFF_WLT);

  hipLaunchKernelGGL(convX,  dim3(2048), dim3(256), 0, stream, x, xh, xlp);
  hipLaunchKernelGGL(convW,  dim3(256),  dim3(256), 0, stream, Wm, wht, wlt);
  hipLaunchKernelGGL(stageA, dim3(1),    dim3(256), 0, stream,
                     tt, ct, lng, lnb, Wq, bq, Wk, bk, ws);
  hipLaunchKernelGGL(stageB, dim3(1024), dim3(256), 0, stream,
                     xh, xlp, wht, wlt, bm, ws);
  hipLaunchKernelGGL(stageC, dim3(8),    dim3(256), 0, stream, ws, out);
}

// Round 3
// 127.579 us; speedup vs baseline: 5.4902x; 2.2015x over previous
//
#include <hip/hip_runtime.h>
#include <hip/hip_bf16.h>
#include <math.h>

#define BB 4
#define NN 2046
#define IND 512
#define DD 1024
#define HH 16
#define SS 2048
#define MM (BB*NN)          // 8184 real rows, padded to 8192
#define MPAD 8192
#define ROWPAD 8256
#define EPSV 1e-5f

// ---- workspace byte offsets ----
#define OFF_U    0                       // float[2][1024]
#define OFF_G    8192                    // float[32]
#define OFF_C2   8320                    // float[32]
#define OFF_S12  24832                   // float[ROWPAD][2]   (rows 0..8193 used)
#define OFF_A    90880                   // float[2][16][ROWPAD]
#define ZERO_SIZE (1147648 - OFF_S12)    // S12 + A regions
#define OFF_XH   1147648                 // bf16[8192][512]
#define OFF_SC   1147648                 // float[8][16][2048] (aliases XH; used after stageB)
#define OFF_XL   9536256                 // bf16[8192][512]
#define OFF_WHT  17924864                // bf16[1024][512]
#define OFF_WLT  18973440                // bf16[1024][512]

typedef float f32x4 __attribute__((ext_vector_type(4)));
typedef __bf16 bf16x8 __attribute__((ext_vector_type(8)));
typedef unsigned short u16x8 __attribute__((ext_vector_type(8)));

__device__ __forceinline__ unsigned short f2bf_rne(float f) {
  unsigned int u = __float_as_uint(f);
  u += 0x7FFFu + ((u >> 16) & 1u);
  return (unsigned short)(u >> 16);
}
__device__ __forceinline__ float bf2f(unsigned short h) {
  return __uint_as_float(((unsigned int)h) << 16);
}

__device__ __forceinline__ float waveSum(float v) {
  #pragma unroll
  for (int m = 32; m >= 1; m >>= 1) v += __shfl_xor(v, m, 64);
  return v;
}

__device__ __forceinline__ float blockReduceSum(float v, volatile float* buf4) {
  #pragma unroll
  for (int m = 32; m >= 1; m >>= 1) v += __shfl_xor(v, m, 64);
  int wid = threadIdx.x >> 6;
  __syncthreads();
  if ((threadIdx.x & 63) == 0) buf4[wid] = v;
  __syncthreads();
  return buf4[0] + buf4[1] + buf4[2] + buf4[3];
}

__device__ __forceinline__ float blockReduceMax(float v, volatile float* buf4) {
  #pragma unroll
  for (int m = 32; m >= 1; m >>= 1) v = fmaxf(v, __shfl_xor(v, m, 64));
  int wid = threadIdx.x >> 6;
  __syncthreads();
  if ((threadIdx.x & 63) == 0) buf4[wid] = v;
  __syncthreads();
  return fmaxf(fmaxf(buf4[0], buf4[1]), fmaxf(buf4[2], buf4[3]));
}

#define GLOAD_LDS16(g, l) \
  __builtin_amdgcn_global_load_lds((const __attribute__((address_space(1))) void*)(g), \
                                   (__attribute__((address_space(3))) void*)(l), 16, 0, 0)

// ---------------------------------------------------------------------------
// convX: x fp32 [8184][512] -> hi/lo bf16 split, rows padded to 8192.
// ---------------------------------------------------------------------------
__global__ __launch_bounds__(256) void convX(const float* __restrict__ x,
                                             unsigned short* __restrict__ xh,
                                             unsigned short* __restrict__ xl) {
  const int t = threadIdx.x;
  const int row = blockIdx.x * 4 + (t >> 6);
  const int c0 = (t & 63) * 8;
  const size_t po = (size_t)row * IND + c0;
  u16x8 hv, lv;
  if (row < MM) {
    const float4* xv = (const float4*)(x + po);
    float4 a = xv[0], b = xv[1];
    float vv[8] = {a.x, a.y, a.z, a.w, b.x, b.y, b.z, b.w};
    #pragma unroll
    for (int i = 0; i < 8; ++i) {
      unsigned short hh = f2bf_rne(vv[i]);
      hv[i] = hh;
      lv[i] = f2bf_rne(vv[i] - bf2f(hh));
    }
  } else {
    #pragma unroll
    for (int i = 0; i < 8; ++i) { hv[i] = 0; lv[i] = 0; }
  }
  *(u16x8*)(xh + po) = hv;
  *(u16x8*)(xl + po) = lv;
}

// ---------------------------------------------------------------------------
// convW: W fp32 [512][1024] -> transposed hi/lo bf16 [1024][512], via LDS tile.
// ---------------------------------------------------------------------------
__global__ __launch_bounds__(256) void convW(const float* __restrict__ Wm,
                                             unsigned short* __restrict__ wht,
                                             unsigned short* __restrict__ wlt) {
  __shared__ float tile[64][65];
  const int t = threadIdx.x;
  const int kb = blockIdx.x >> 4, nb = blockIdx.x & 15;
  const int k0 = kb * 64, n0 = nb * 64;
  #pragma unroll
  for (int q = 0; q < 16; ++q) {
    int lin = q * 256 + t;
    int kk = lin >> 6, nn = lin & 63;
    tile[kk][nn] = Wm[(size_t)(k0 + kk) * DD + n0 + nn];
  }
  __syncthreads();
  #pragma unroll
  for (int q = 0; q < 16; ++q) {
    int lin = q * 256 + t;
    int nn = lin >> 6, kk = lin & 63;
    float v = tile[kk][nn];
    unsigned short hh = f2bf_rne(v);
    wht[(size_t)(n0 + nn) * IND + k0 + kk] = hh;
    wlt[(size_t)(n0 + nn) * IND + k0 + kk] = f2bf_rne(v - bf2f(hh));
  }
}

// ---------------------------------------------------------------------------
// stageA: one block per (s,h). LN moments of the special row, q, wtil,
// u-vector, G/C2 constants, special-row A and S12 entries.
// ---------------------------------------------------------------------------
__global__ __launch_bounds__(64) void stageA(
    const float* __restrict__ tt, const float* __restrict__ ct,
    const float* __restrict__ lng, const float* __restrict__ lnb,
    const float* __restrict__ Wq, const float* __restrict__ bq,
    const float* __restrict__ Wk, const float* __restrict__ bk,
    float* __restrict__ ws) {
  __shared__ float hsm[64], qsm[64];
  const int s = blockIdx.x >> 4, h = blockIdx.x & 15;
  const int e = threadIdx.x;
  const float* src = s ? ct : tt;
  float* U   = ws + OFF_U/4;
  float* Gp  = ws + OFF_G/4;
  float* C2p = ws + OFF_C2/4;
  float* s12 = ws + OFF_S12/4;
  float* Ap  = ws + OFF_A/4;

  float s1 = 0.f, s2 = 0.f;
  #pragma unroll
  for (int i = 0; i < 16; ++i) { float v = src[i*64 + e]; s1 += v; s2 += v*v; }
  s1 = waveSum(s1); s2 = waveSum(s2);
  if (h == 0 && e == 0) {
    s12[(MPAD + s)*2 + 0] = s1;
    s12[(MPAD + s)*2 + 1] = s2;
  }
  const float mu = s1 * (1.f/DD);
  const float var = s2 * (1.f/DD) - mu*mu;
  const float rstd = rsqrtf(var + EPSV);

  const int d0 = h * 64;
  hsm[e] = (src[d0+e] - mu) * rstd * lng[d0+e] + lnb[d0+e];
  __syncthreads();
  float qv = bq[d0+e];
  #pragma unroll 8
  for (int d = 0; d < 64; ++d) qv += hsm[d] * Wq[(size_t)(d0+d)*64 + e];
  qsm[e] = qv;
  __syncthreads();
  float wt = 0.f;
  #pragma unroll 8
  for (int ee = 0; ee < 64; ++ee) wt += Wk[(size_t)(d0+e)*64 + ee] * qsm[ee];
  wt *= 0.125f;
  const float c = waveSum(qsm[e] * bk[d0+e]) * 0.125f;
  const float u = lng[d0+e] * wt;
  U[s*DD + d0 + e] = u;
  const float G  = waveSum(lng[d0+e] * wt);
  const float C  = waveSum(lnb[d0+e] * wt);
  const float a0 = waveSum(tt[d0+e] * u);
  const float a1 = waveSum(ct[d0+e] * u);
  if (e == 0) {
    Gp[s*16+h]  = G;
    C2p[s*16+h] = C + c;
    Ap[(size_t)(s*16+h)*ROWPAD + MPAD + 0] = a0;
    Ap[(size_t)(s*16+h)*ROWPAD + MPAD + 1] = a1;
  }
}

// ---------------------------------------------------------------------------
// stageB: 128x128 tile MFMA GEMM, K=512 (BK=64), split-bf16 (3 products),
// LDS-staged with global_load_lds + XOR swizzle. Fused S1/S2/A epilogue,
// atomicAdd partials. bid = n*64 + m  (m-panel's 8 n-blocks share an XCD).
// ---------------------------------------------------------------------------
__global__ __launch_bounds__(256, 2) void stageB(
    const unsigned short* __restrict__ xh, const unsigned short* __restrict__ xl,
    const unsigned short* __restrict__ wht, const unsigned short* __restrict__ wlt,
    const float* __restrict__ bmap, float* __restrict__ ws) {
  __shared__ unsigned short Ash[128*64], Asl[128*64], Bsh[128*64], Bsl[128*64];
  __shared__ float s12w[4][64][2];
  __shared__ float aw[4][64][2];
  const int t = threadIdx.x, wave = t >> 6, lane = t & 63;
  const int lj = lane & 15, lg = lane >> 4;
  const int mb = blockIdx.x & 63, nb = blockIdx.x >> 6;
  const int m0 = mb * 128, n0 = nb * 128;
  const int wr = wave >> 1, wc = wave & 1;
  const float* U = ws + OFF_U/4;
  float* s12 = ws + OFF_S12/4;
  float* Ap  = ws + OFF_A/4;

  f32x4 acc[4][4];
  #pragma unroll
  for (int i = 0; i < 4; ++i)
    #pragma unroll
    for (int j = 0; j < 4; ++j) acc[i][j] = (f32x4){0.f,0.f,0.f,0.f};

  const int rr = lane >> 3;               // 0..7: row within 8-row group
  const int slot = (lane & 7) ^ rr;       // pre-swizzled global 16B-slot

  for (int ks = 0; ks < 8; ++ks) {
    const size_t kofs = (size_t)ks * 64;
    #pragma unroll
    for (int q = 0; q < 4; ++q) {
      const int r = wave*32 + q*8 + rr;
      const size_t go = (size_t)(m0 + r)*IND + kofs + slot*8;
      const size_t gn = (size_t)(n0 + r)*IND + kofs + slot*8;
      const int lo = (wave*32 + q*8) * 64;    // element offset of row-group base
      GLOAD_LDS16(xh  + go, Ash + lo);
      GLOAD_LDS16(xl  + go, Asl + lo);
      GLOAD_LDS16(wht + gn, Bsh + lo);
      GLOAD_LDS16(wlt + gn, Bsl + lo);
    }
    __syncthreads();
    #pragma unroll
    for (int kf = 0; kf < 2; ++kf) {
      const int sl = kf*4 + lg;
      bf16x8 afh[4], afl[4], bfh[4], bfl[4];
      #pragma unroll
      for (int i = 0; i < 4; ++i) {
        const int r = wr*64 + i*16 + lj;
        const int byt = r*128 + ((sl ^ (r & 7)) * 16);
        afh[i] = *(const bf16x8*)((const char*)Ash + byt);
        afl[i] = *(const bf16x8*)((const char*)Asl + byt);
      }
      #pragma unroll
      for (int j = 0; j < 4; ++j) {
        const int r = wc*64 + j*16 + lj;
        const int byt = r*128 + ((sl ^ (r & 7)) * 16);
        bfh[j] = *(const bf16x8*)((const char*)Bsh + byt);
        bfl[j] = *(const bf16x8*)((const char*)Bsl + byt);
      }
      #pragma unroll
      for (int i = 0; i < 4; ++i)
        #pragma unroll
        for (int j = 0; j < 4; ++j) {
          acc[i][j] = __builtin_amdgcn_mfma_f32_16x16x32_bf16(afh[i], bfh[j], acc[i][j], 0, 0, 0);
          acc[i][j] = __builtin_amdgcn_mfma_f32_16x16x32_bf16(afl[i], bfh[j], acc[i][j], 0, 0, 0);
          acc[i][j] = __builtin_amdgcn_mfma_f32_16x16x32_bf16(afh[i], bfl[j], acc[i][j], 0, 0, 0);
        }
    }
    __syncthreads();
  }

  // ---- fused epilogue: per-row S1,S2 and per-(s,head) A partials ----
  float s1p[16], s2p[16], a0p[16], a1p[16];
  #pragma unroll
  for (int p = 0; p < 16; ++p) { s1p[p]=0.f; s2p[p]=0.f; a0p[p]=0.f; a1p[p]=0.f; }
  #pragma unroll
  for (int j = 0; j < 4; ++j) {
    const int gc = n0 + wc*64 + j*16 + lj;
    const float bmv = bmap[gc];
    const float u0 = U[gc], u1 = U[DD + gc];
    #pragma unroll
    for (int i = 0; i < 4; ++i)
      #pragma unroll
      for (int r = 0; r < 4; ++r) {
        const float tok = acc[i][j][r] + bmv;
        const int p = i*4 + r;
        s1p[p] += tok; s2p[p] += tok*tok;
        a0p[p] += tok*u0; a1p[p] += tok*u1;
      }
  }
  #pragma unroll
  for (int msk = 8; msk >= 1; msk >>= 1)
    #pragma unroll
    for (int p = 0; p < 16; ++p) {
      s1p[p] += __shfl_xor(s1p[p], msk, 64);
      s2p[p] += __shfl_xor(s2p[p], msk, 64);
      a0p[p] += __shfl_xor(a0p[p], msk, 64);
      a1p[p] += __shfl_xor(a1p[p], msk, 64);
    }
  if (lj == 0) {
    #pragma unroll
    for (int p = 0; p < 16; ++p) {
      const int rl = (p>>2)*16 + lg*4 + (p&3);   // row within wave (0..63)
      s12w[wave][rl][0] = s1p[p];
      s12w[wave][rl][1] = s2p[p];
      aw[wave][rl][0]   = a0p[p];
      aw[wave][rl][1]   = a1p[p];
    }
  }
  __syncthreads();
  if (t < 128) {
    const int rloc = t, wrg = rloc >> 6, rw = rloc & 63;
    const int grow = m0 + rloc;
    const int h0 = n0 >> 6;
    atomicAdd(&s12[grow*2+0], s12w[wrg*2+0][rw][0] + s12w[wrg*2+1][rw][0]);
    atomicAdd(&s12[grow*2+1], s12w[wrg*2+0][rw][1] + s12w[wrg*2+1][rw][1]);
    atomicAdd(&Ap[(size_t)(0*16 + h0    )*ROWPAD + grow], aw[wrg*2+0][rw][0]);
    atomicAdd(&Ap[(size_t)(1*16 + h0    )*ROWPAD + grow], aw[wrg*2+0][rw][1]);
    atomicAdd(&Ap[(size_t)(0*16 + h0 + 1)*ROWPAD + grow], aw[wrg*2+1][rw][0]);
    atomicAdd(&Ap[(size_t)(1*16 + h0 + 1)*ROWPAD + grow], aw[wrg*2+1][rw][1]);
  }
}

// ---------------------------------------------------------------------------
// stageC1: one block per (b,s,h): reconstruct scores, softmax, write probs.
// ---------------------------------------------------------------------------
__global__ __launch_bounds__(256) void stageC1(const float* __restrict__ ws,
                                               float* __restrict__ sc) {
  __shared__ float rbuf[4];
  const int bid = blockIdx.x;            // (b*2+s)*16 + h
  const int h = bid & 15, bs = bid >> 4, b = bs >> 1, s = bs & 1;
  const int t = threadIdx.x;
  const float* s12 = ws + OFF_S12/4;
  const float* Ah  = ws + OFF_A/4 + (size_t)(s*16+h)*ROWPAD;
  const float Gh = ws[OFF_G/4 + s*16+h], Ch = ws[OFF_C2/4 + s*16+h];

  float v[8];
  float mx = -3.0e38f;
  #pragma unroll
  for (int i = 0; i < 8; ++i) {
    const int p = i*256 + t;
    const int r = (p == 0) ? MPAD : (p == 1) ? (MPAD+1) : (b*NN + p - 2);
    const float s1 = s12[r*2], s2 = s12[r*2+1];
    const float mu = s1 * (1.f/DD);
    const float var = s2 * (1.f/DD) - mu*mu;
    const float rstd = rsqrtf(var + EPSV);
    v[i] = rstd * (Ah[r] - mu*Gh) + Ch;
    mx = fmaxf(mx, v[i]);
  }
  mx = blockReduceMax(mx, rbuf);
  float sum = 0.f;
  #pragma unroll
  for (int i = 0; i < 8; ++i) { v[i] = __expf(v[i] - mx); sum += v[i]; }
  sum = blockReduceSum(sum, rbuf);
  const float inv = 1.f / (16.f * sum);
  float* outp = sc + (size_t)bid * SS;
  #pragma unroll
  for (int i = 0; i < 8; ++i) outp[i*256 + t] = v[i] * inv;
}

// ---------------------------------------------------------------------------
// stageC2: mean over heads (1/16 already folded into C1's normalization).
// ---------------------------------------------------------------------------
__global__ __launch_bounds__(256) void stageC2(const float* __restrict__ sc,
                                               float* __restrict__ out) {
  const int idx = blockIdx.x * 256 + threadIdx.x;   // 0..16383
  const int pos = idx & 2047, bs = idx >> 11;
  const int b = bs >> 1, s = bs & 1;
  const float* base = sc + (size_t)bs*16*SS + pos;
  float acc = 0.f;
  #pragma unroll
  for (int h = 0; h < 16; ++h) acc += base[(size_t)h*SS];
  out[(size_t)s*(BB*SS) + (size_t)b*SS + pos] = acc;
}

extern "C" void kernel_launch(void* const* d_in, const int* in_sizes, int n_in,
                              void* d_out, int out_size, void* d_ws, size_t ws_size,
                              hipStream_t stream) {
  const float* x   = (const float*)d_in[0];
  const float* Wm  = (const float*)d_in[1];
  const float* bm  = (const float*)d_in[2];
  const float* tt  = (const float*)d_in[3];
  const float* ct  = (const float*)d_in[4];
  const float* lng = (const float*)d_in[5];
  const float* lnb = (const float*)d_in[6];
  const float* Wq  = (const float*)d_in[7];
  const float* bq  = (const float*)d_in[8];
  const float* Wk  = (const float*)d_in[9];
  const float* bk  = (const float*)d_in[10];
  char* wsb = (char*)d_ws;
  float* ws = (float*)d_ws;
  float* out = (float*)d_out;

  unsigned short* xh  = (unsigned short*)(wsb + OFF_XH);
  unsigned short* xlp = (unsigned short*)(wsb + OFF_XL);
  unsigned short* wht = (unsigned short*)(wsb + OFF_WHT);
  unsigned short* wlt = (unsigned short*)(wsb + OFF_WLT);
  float* sc = (float*)(wsb + OFF_SC);

  hipMemsetAsync(wsb + OFF_S12, 0, ZERO_SIZE, stream);
  hipLaunchKernelGGL(convX,   dim3(2048), dim3(256), 0, stream, x, xh, xlp);
  hipLaunchKernelGGL(convW,   dim3(128),  dim3(256), 0, stream, Wm, wht, wlt);
  hipLaunchKernelGGL(stageA,  dim3(32),   dim3(64),  0, stream,
                     tt, ct, lng, lnb, Wq, bq, Wk, bk, ws);
  hipLaunchKernelGGL(stageB,  dim3(512),  dim3(256), 0, stream,
                     xh, xlp, wht, wlt, bm, ws);
  hipLaunchKernelGGL(stageC1, dim3(128),  dim3(256), 0, stream, ws, sc);
  hipLaunchKernelGGL(stageC2, dim3(64),   dim3(256), 0, stream, sc, out);
}

// Round 4
// 114.184 us; speedup vs baseline: 6.1342x; 1.1173x over previous
//
#include <hip/hip_runtime.h>
#include <hip/hip_bf16.h>
#include <math.h>

#define BB 4
#define NN 2046
#define IND 512
#define DD 1024
#define HH 16
#define SS 2048
#define MM (BB*NN)          // 8184 real rows, padded to 8192
#define MPAD 8192
#define ROWPAD 8256
#define EPSV 1e-5f

// ---- workspace FLOAT offsets ----
#define OFF_U    0                   // float[2][1024]
#define OFF_G    2048                // float[32]
#define OFF_C2   2080                // float[32]
#define OFF_S12  4096                // float[ROWPAD][2] (rows 0..8193 used)
#define OFF_A    (4096 + 2*ROWPAD)   // float[32][ROWPAD] = 20608
// ---- byte offsets for bf16 buffers ----
#define OFF_XH_B  1139200                      // bf16[8192][512]
#define OFF_WHT_B (OFF_XH_B + MPAD*IND*2)      // bf16[1024][512]
#define OFF_WLT_B (OFF_WHT_B + DD*IND*2)       // bf16[1024][512]

typedef float f32x4 __attribute__((ext_vector_type(4)));
typedef __bf16 bf16x8 __attribute__((ext_vector_type(8)));
typedef unsigned short u16x8 __attribute__((ext_vector_type(8)));

__device__ __forceinline__ unsigned short f2bf_rne(float f) {
  unsigned int u = __float_as_uint(f);
  u += 0x7FFFu + ((u >> 16) & 1u);
  return (unsigned short)(u >> 16);
}

__device__ __forceinline__ float waveSum(float v) {
  #pragma unroll
  for (int m = 32; m >= 1; m >>= 1) v += __shfl_xor(v, m, 64);
  return v;
}

__device__ __forceinline__ float blockReduceSum(float v, volatile float* buf4) {
  #pragma unroll
  for (int m = 32; m >= 1; m >>= 1) v += __shfl_xor(v, m, 64);
  int wid = threadIdx.x >> 6;
  __syncthreads();
  if ((threadIdx.x & 63) == 0) buf4[wid] = v;
  __syncthreads();
  return buf4[0] + buf4[1] + buf4[2] + buf4[3];
}

#define GLOAD_LDS16(g, l) \
  __builtin_amdgcn_global_load_lds((const __attribute__((address_space(1))) void*)(g), \
                                   (__attribute__((address_space(3))) void*)(l), 16, 0, 0)

// ---------------------------------------------------------------------------
// prep: fused independent preprocessing, one dispatch.
//   [0,2048)     convX: x fp32 -> xh bf16 (hi only), rows padded to 8192
//   [2048,2176)  convW: W fp32 [512][1024] -> transposed hi/lo bf16 [1024][512]
//   [2176,2184)  stageA: 4 waves/block, one (s,h) each: LN consts, u, G, C2,
//                special-row S12/A entries
//   [2184,2252)  zero S12 rows [0,8192) and A rows [0,8192) per slice
//   [2252,2256)  zero d_out
// ---------------------------------------------------------------------------
__global__ __launch_bounds__(256) void prep(
    const float* __restrict__ x, const float* __restrict__ Wm,
    const float* __restrict__ tt, const float* __restrict__ ct,
    const float* __restrict__ lng, const float* __restrict__ lnb,
    const float* __restrict__ Wq, const float* __restrict__ bq,
    const float* __restrict__ Wk, const float* __restrict__ bk,
    unsigned short* __restrict__ xh, unsigned short* __restrict__ wht,
    unsigned short* __restrict__ wlt, float* __restrict__ ws,
    float* __restrict__ out) {
  __shared__ float tile[64][65];
  __shared__ float hq[4][64];
  __shared__ float qs[4][64];
  const int bid = blockIdx.x;
  const int t = threadIdx.x;

  if (bid < 2048) {                       // ---- convX (hi only) ----
    const int row = bid * 4 + (t >> 6);
    const int c0 = (t & 63) * 8;
    const size_t po = (size_t)row * IND + c0;
    u16x8 hv;
    if (row < MM) {
      const float4* xv = (const float4*)(x + po);
      float4 a = xv[0], b = xv[1];
      float vv[8] = {a.x, a.y, a.z, a.w, b.x, b.y, b.z, b.w};
      #pragma unroll
      for (int i = 0; i < 8; ++i) hv[i] = f2bf_rne(vv[i]);
    } else {
      #pragma unroll
      for (int i = 0; i < 8; ++i) hv[i] = 0;
    }
    *(u16x8*)(xh + po) = hv;
  } else if (bid < 2176) {                // ---- convW (hi+lo, transpose) ----
    const int b2 = bid - 2048;
    const int kb = b2 >> 4, nb = b2 & 15;
    const int k0 = kb * 64, n0 = nb * 64;
    #pragma unroll
    for (int q = 0; q < 16; ++q) {
      int lin = q * 256 + t;
      int kk = lin >> 6, nn = lin & 63;
      tile[kk][nn] = Wm[(size_t)(k0 + kk) * DD + n0 + nn];
    }
    __syncthreads();
    #pragma unroll
    for (int q = 0; q < 16; ++q) {
      int lin = q * 256 + t;
      int nn = lin >> 6, kk = lin & 63;
      float v = tile[kk][nn];
      unsigned short hh = f2bf_rne(v);
      wht[(size_t)(n0 + nn) * IND + k0 + kk] = hh;
      wlt[(size_t)(n0 + nn) * IND + k0 + kk] =
          f2bf_rne(v - __uint_as_float(((unsigned int)hh) << 16));
    }
  } else if (bid < 2184) {                // ---- stageA (per-wave) ----
    const int w = t >> 6, e = t & 63;
    const int sh = (bid - 2176) * 4 + w;
    const int s = sh >> 4, h = sh & 15;
    const float* src = s ? ct : tt;
    float* U   = ws + OFF_U;
    float* s12 = ws + OFF_S12;
    float* Ap  = ws + OFF_A;

    float s1 = 0.f, s2 = 0.f;
    #pragma unroll
    for (int i = 0; i < 16; ++i) { float v = src[i*64 + e]; s1 += v; s2 += v*v; }
    s1 = waveSum(s1); s2 = waveSum(s2);
    if (h == 0 && e == 0) {
      s12[(MPAD + s)*2 + 0] = s1;
      s12[(MPAD + s)*2 + 1] = s2;
    }
    const float mu = s1 * (1.f/DD);
    const float var = s2 * (1.f/DD) - mu*mu;
    const float rstd = rsqrtf(var + EPSV);
    const int d0 = h * 64;
    hq[w][e] = (src[d0+e] - mu) * rstd * lng[d0+e] + lnb[d0+e];
    float qv = bq[d0+e];
    #pragma unroll 8
    for (int d = 0; d < 64; ++d) qv += hq[w][d] * Wq[(size_t)(d0+d)*64 + e];
    qs[w][e] = qv;
    float wt = 0.f;
    #pragma unroll 8
    for (int ee = 0; ee < 64; ++ee) wt += Wk[(size_t)(d0+e)*64 + ee] * qs[w][ee];
    wt *= 0.125f;
    const float c = waveSum(qs[w][e] * bk[d0+e]) * 0.125f;
    const float u = lng[d0+e] * wt;
    U[s*DD + d0 + e] = u;
    const float G  = waveSum(lng[d0+e] * wt);
    const float C  = waveSum(lnb[d0+e] * wt);
    const float a0 = waveSum(tt[d0+e] * u);
    const float a1 = waveSum(ct[d0+e] * u);
    if (e == 0) {
      ws[OFF_G  + sh] = G;
      ws[OFF_C2 + sh] = C + c;
      Ap[(size_t)sh*ROWPAD + MPAD + 0] = a0;
      Ap[(size_t)sh*ROWPAD + MPAD + 1] = a1;
    }
  } else if (bid < 2252) {                // ---- zero S12 + A accum rows ----
    const int j = (bid - 2184) * 4096 + t * 16;
    const float4 z = make_float4(0.f, 0.f, 0.f, 0.f);
    #pragma unroll
    for (int q = 0; q < 4; ++q) {
      const int f = j + q * 4;
      if (f < 16384) {
        *(float4*)(ws + OFF_S12 + f) = z;
      } else {
        const int g = f - 16384;
        const int sl = g >> 13, rw = g & 8191;
        *(float4*)(ws + OFF_A + (size_t)sl*ROWPAD + rw) = z;
      }
    }
  } else {                                // ---- zero d_out ----
    const int f = (bid - 2252) * 4096 + t * 16;
    const float4 z = make_float4(0.f, 0.f, 0.f, 0.f);
    #pragma unroll
    for (int q = 0; q < 4; ++q) *(float4*)(out + f + q*4) = z;
  }
}

// ---------------------------------------------------------------------------
// stageB: 128x128 tile MFMA GEMM, K=512 (BK=64), 2-product split-bf16
// (tok = ah*(bh+bl)). LDS-staged via global_load_lds + XOR swizzle.
// Fused S1/S2/A epilogue with atomicAdd partials. bid = n*64 + m.
// ---------------------------------------------------------------------------
__global__ __launch_bounds__(256, 2) void stageB(
    const unsigned short* __restrict__ xh,
    const unsigned short* __restrict__ wht, const unsigned short* __restrict__ wlt,
    const float* __restrict__ bmap, float* __restrict__ ws) {
  __shared__ unsigned short Ash[128*64], Bsh[128*64], Bsl[128*64];
  __shared__ float s12w[4][64][2];
  __shared__ float aw[4][64][2];
  const int t = threadIdx.x, wave = t >> 6, lane = t & 63;
  const int lj = lane & 15, lg = lane >> 4;
  const int mb = blockIdx.x & 63, nb = blockIdx.x >> 6;
  const int m0 = mb * 128, n0 = nb * 128;
  const int wr = wave >> 1, wc = wave & 1;
  const float* U = ws + OFF_U;
  float* s12 = ws + OFF_S12;
  float* Ap  = ws + OFF_A;

  f32x4 acc[4][4];
  #pragma unroll
  for (int i = 0; i < 4; ++i)
    #pragma unroll
    for (int j = 0; j < 4; ++j) acc[i][j] = (f32x4){0.f,0.f,0.f,0.f};

  const int rr = lane >> 3;               // row within 8-row group
  const int slot = (lane & 7) ^ rr;       // pre-swizzled global 16B-slot

  for (int ks = 0; ks < 8; ++ks) {
    const size_t kofs = (size_t)ks * 64;
    #pragma unroll
    for (int q = 0; q < 4; ++q) {
      const int r = wave*32 + q*8 + rr;
      const size_t go = (size_t)(m0 + r)*IND + kofs + slot*8;
      const size_t gn = (size_t)(n0 + r)*IND + kofs + slot*8;
      const int lo = (wave*32 + q*8) * 64;
      GLOAD_LDS16(xh  + go, Ash + lo);
      GLOAD_LDS16(wht + gn, Bsh + lo);
      GLOAD_LDS16(wlt + gn, Bsl + lo);
    }
    __syncthreads();
    #pragma unroll
    for (int kf = 0; kf < 2; ++kf) {
      const int sl = kf*4 + lg;
      bf16x8 afh[4], bfh[4], bfl[4];
      #pragma unroll
      for (int i = 0; i < 4; ++i) {
        const int r = wr*64 + i*16 + lj;
        const int byt = r*128 + ((sl ^ (r & 7)) * 16);
        afh[i] = *(const bf16x8*)((const char*)Ash + byt);
      }
      #pragma unroll
      for (int j = 0; j < 4; ++j) {
        const int r = wc*64 + j*16 + lj;
        const int byt = r*128 + ((sl ^ (r & 7)) * 16);
        bfh[j] = *(const bf16x8*)((const char*)Bsh + byt);
        bfl[j] = *(const bf16x8*)((const char*)Bsl + byt);
      }
      #pragma unroll
      for (int i = 0; i < 4; ++i)
        #pragma unroll
        for (int j = 0; j < 4; ++j) {
          acc[i][j] = __builtin_amdgcn_mfma_f32_16x16x32_bf16(afh[i], bfh[j], acc[i][j], 0, 0, 0);
          acc[i][j] = __builtin_amdgcn_mfma_f32_16x16x32_bf16(afh[i], bfl[j], acc[i][j], 0, 0, 0);
        }
    }
    __syncthreads();
  }

  // ---- fused epilogue: per-row S1,S2 and per-(s,head) A partials ----
  float s1p[16], s2p[16], a0p[16], a1p[16];
  #pragma unroll
  for (int p = 0; p < 16; ++p) { s1p[p]=0.f; s2p[p]=0.f; a0p[p]=0.f; a1p[p]=0.f; }
  #pragma unroll
  for (int j = 0; j < 4; ++j) {
    const int gc = n0 + wc*64 + j*16 + lj;
    const float bmv = bmap[gc];
    const float u0 = U[gc], u1 = U[DD + gc];
    #pragma unroll
    for (int i = 0; i < 4; ++i)
      #pragma unroll
      for (int r = 0; r < 4; ++r) {
        const float tok = acc[i][j][r] + bmv;
        const int p = i*4 + r;
        s1p[p] += tok; s2p[p] += tok*tok;
        a0p[p] += tok*u0; a1p[p] += tok*u1;
      }
  }
  #pragma unroll
  for (int msk = 8; msk >= 1; msk >>= 1)
    #pragma unroll
    for (int p = 0; p < 16; ++p) {
      s1p[p] += __shfl_xor(s1p[p], msk, 64);
      s2p[p] += __shfl_xor(s2p[p], msk, 64);
      a0p[p] += __shfl_xor(a0p[p], msk, 64);
      a1p[p] += __shfl_xor(a1p[p], msk, 64);
    }
  if (lj == 0) {
    #pragma unroll
    for (int p = 0; p < 16; ++p) {
      const int rl = (p>>2)*16 + lg*4 + (p&3);
      s12w[wave][rl][0] = s1p[p];
      s12w[wave][rl][1] = s2p[p];
      aw[wave][rl][0]   = a0p[p];
      aw[wave][rl][1]   = a1p[p];
    }
  }
  __syncthreads();
  if (t < 128) {
    const int rloc = t, wrg = rloc >> 6, rw = rloc & 63;
    const int grow = m0 + rloc;
    const int h0 = n0 >> 6;
    atomicAdd(&s12[grow*2+0], s12w[wrg*2+0][rw][0] + s12w[wrg*2+1][rw][0]);
    atomicAdd(&s12[grow*2+1], s12w[wrg*2+0][rw][1] + s12w[wrg*2+1][rw][1]);
    atomicAdd(&Ap[(size_t)(0*16 + h0    )*ROWPAD + grow], aw[wrg*2+0][rw][0]);
    atomicAdd(&Ap[(size_t)(1*16 + h0    )*ROWPAD + grow], aw[wrg*2+0][rw][1]);
    atomicAdd(&Ap[(size_t)(0*16 + h0 + 1)*ROWPAD + grow], aw[wrg*2+1][rw][0]);
    atomicAdd(&Ap[(size_t)(1*16 + h0 + 1)*ROWPAD + grow], aw[wrg*2+1][rw][1]);
  }
}

// ---------------------------------------------------------------------------
// stageC1: one block per (b,s,h): reconstruct scores, raw-exp softmax
// (scores are O(+-5); no max pass), atomicAdd head-mean into d_out.
// ---------------------------------------------------------------------------
__global__ __launch_bounds__(256) void stageC1(const float* __restrict__ ws,
                                               float* __restrict__ out) {
  __shared__ float rbuf[4];
  const int bid = blockIdx.x;            // (b*2+s)*16 + h
  const int h = bid & 15, bs = bid >> 4, b = bs >> 1, s = bs & 1;
  const int t = threadIdx.x;
  const float* s12 = ws + OFF_S12;
  const float* Ah  = ws + OFF_A + (size_t)(s*16+h)*ROWPAD;
  const float Gh = ws[OFF_G + s*16+h], Ch = ws[OFF_C2 + s*16+h];

  float v[8];
  float sum = 0.f;
  #pragma unroll
  for (int i = 0; i < 8; ++i) {
    const int p = i*256 + t;
    const int r = (p == 0) ? MPAD : (p == 1) ? (MPAD+1) : (b*NN + p - 2);
    const float s1 = s12[r*2], s2 = s12[r*2+1];
    const float mu = s1 * (1.f/DD);
    const float var = s2 * (1.f/DD) - mu*mu;
    const float rstd = rsqrtf(var + EPSV);
    const float sc = fminf(rstd * (Ah[r] - mu*Gh) + Ch, 60.f);
    v[i] = __expf(sc);
    sum += v[i];
  }
  sum = blockReduceSum(sum, rbuf);
  const float inv = 1.f / (16.f * sum);
  float* op = out + (size_t)s*(BB*SS) + (size_t)b*SS;
  #pragma unroll
  for (int i = 0; i < 8; ++i) atomicAdd(&op[i*256 + t], v[i] * inv);
}

extern "C" void kernel_launch(void* const* d_in, const int* in_sizes, int n_in,
                              void* d_out, int out_size, void* d_ws, size_t ws_size,
                              hipStream_t stream) {
  const float* x   = (const float*)d_in[0];
  const float* Wm  = (const float*)d_in[1];
  const float* bm  = (const float*)d_in[2];
  const float* tt  = (const float*)d_in[3];
  const float* ct  = (const float*)d_in[4];
  const float* lng = (const float*)d_in[5];
  const float* lnb = (const float*)d_in[6];
  const float* Wq  = (const float*)d_in[7];
  const float* bq  = (const float*)d_in[8];
  const float* Wk  = (const float*)d_in[9];
  const float* bk  = (const float*)d_in[10];
  char* wsb = (char*)d_ws;
  float* ws = (float*)d_ws;
  float* out = (float*)d_out;

  unsigned short* xh  = (unsigned short*)(wsb + OFF_XH_B);
  unsigned short* wht = (unsigned short*)(wsb + OFF_WHT_B);
  unsigned short* wlt = (unsigned short*)(wsb + OFF_WLT_B);

  hipLaunchKernelGGL(prep,    dim3(2256), dim3(256), 0, stream,
                     x, Wm, tt, ct, lng, lnb, Wq, bq, Wk, bk,
                     xh, wht, wlt, ws, out);
  hipLaunchKernelGGL(stageB,  dim3(512),  dim3(256), 0, stream,
                     xh, wht, wlt, bm, ws);
  hipLaunchKernelGGL(stageC1, dim3(128),  dim3(256), 0, stream, ws, out);
}